// Round 5
// baseline (104.166 us; speedup 1.0000x reference)
//
#include <hip/hip_runtime.h>
#include <math.h>

#define NB 8
#define NN 512
#define D 128
#define TI 8          // query rows per k2 block
#define K1R 8         // rows per k1 block
#define LN_EPS 1e-5f
#define SCALE 0.08838834764831845f  // 1/sqrt(128)

#define KE_BLOCKS 2048
#define KE_NTH (KE_BLOCKS * 256)          // 524288 threads
#define TOT_F4 (NB * NN * NN * 4)         // 8388608 float4 in edge_feats

typedef float f32x4 __attribute__((ext_vector_type(4)));

__device__ __forceinline__ float dotv(f32x4 a, f32x4 b) {
    f32x4 m = a * b;
    return m.x + m.y + m.z + m.w;
}
__device__ __forceinline__ float dot4(float4 a, float4 b) {
    return a.x * b.x + a.y * b.y + a.z * b.z + a.w * b.w;
}

// ---------------- Kernel E: s_e[b,i,j] = edge_feats[b,i,j,:] . a_e ----------
// Pure streaming, fill-like shape: lane-contiguous float4 loads, 4-lane reduce.
// NOTE: launched 3x this round (idempotent) purely to measure its steady-state
// cost via dur_us subtraction vs round 3: dur5 = dur3 + 2*ke.
__global__ __launch_bounds__(256) void ke_scores(
    const float* __restrict__ ef, const float* __restrict__ a_e,
    float* __restrict__ se_ws)
{
    const int g = blockIdx.x * 256 + threadIdx.x;
    const int c = g & 3;                       // which quarter of the 16-dim edge
    const f32x4 A = ((const f32x4*)a_e)[c];    // per-thread constant
    const f32x4* ef4 = (const f32x4*)ef;
#pragma unroll 4
    for (int k = 0; k < TOT_F4 / KE_NTH; ++k) {
        const size_t f = (size_t)k * KE_NTH + g;     // lane-contiguous
        const f32x4 v = ef4[f];
        float p = dotv(v, A);
        p += __shfl_xor(p, 1);
        p += __shfl_xor(p, 2);
        if (c == 0) se_ws[f >> 2] = p;               // 16 lanes/wave, 64B/wave
    }
}

// ---------------- Kernel 1: h = x @ W^T, s_i, s_j ---------------------------
// grid: 512 blocks (8 rows each), block: 256. W staged in LDS (swizzled).
__global__ __launch_bounds__(256) void k1_proj(
    const float* __restrict__ x, const float* __restrict__ W,
    const float* __restrict__ a_src, const float* __restrict__ a_dst,
    float* __restrict__ h_ws, float* __restrict__ si_ws, float* __restrict__ sj_ws)
{
    __shared__ __align__(16) float4 Wl[128][32];   // [o][q ^ (o&7)] swizzle
    __shared__ __align__(16) float4 xl[K1R][32];
    __shared__ float redk[K1R][2][2];

    const int t = threadIdx.x;
    const int row0 = blockIdx.x * K1R;

    const float4* Wg = (const float4*)W;
#pragma unroll
    for (int k = 0; k < 16; ++k) {
        const int f = t + 256 * k;          // 4096 float4 of W
        const int o = f >> 5, q = f & 31;
        Wl[o][q ^ (o & 7)] = Wg[f];
    }
    xl[t >> 5][t & 31] = ((const float4*)(x + (size_t)row0 * D))[t];  // 256 float4
    __syncthreads();

    const int o = t & 127;
    const int rb = (t >> 7) * (K1R / 2);    // rows 0-3 or 4-7
    float acc[K1R / 2] = {0.f, 0.f, 0.f, 0.f};
#pragma unroll
    for (int q = 0; q < 32; ++q) {
        const float4 wv = Wl[o][q ^ (o & 7)];
#pragma unroll
        for (int r = 0; r < K1R / 2; ++r) acc[r] += dot4(wv, xl[rb + r][q]);
    }
    const float as = a_src[o], ad = a_dst[o];
#pragma unroll
    for (int r = 0; r < K1R / 2; ++r) {
        h_ws[(size_t)(row0 + rb + r) * D + o] = acc[r];
        float vs = acc[r] * as, vd = acc[r] * ad;
#pragma unroll
        for (int m = 32; m >= 1; m >>= 1) {
            vs += __shfl_xor(vs, m);
            vd += __shfl_xor(vd, m);
        }
        if ((t & 63) == 0) {
            redk[rb + r][0][(t >> 6) & 1] = vs;
            redk[rb + r][1][(t >> 6) & 1] = vd;
        }
    }
    __syncthreads();
    if (t < K1R) si_ws[row0 + t] = redk[t][0][0] + redk[t][0][1];
    else if (t < 2 * K1R) {
        const int r = t - K1R;
        sj_ws[row0 + r] = redk[r][1][0] + redk[r][1][1];
    }
}

// ---------------- Kernel 2: softmax + PV + LayerNorm ------------------------
// grid: 8 * 64 = 512 blocks (TI=8 rows each), block: 256
__global__ __launch_bounds__(256) void k2_attn(
    const float* __restrict__ se_ws,
    const float* __restrict__ gamma, const float* __restrict__ beta,
    const float* __restrict__ h_ws, const float* __restrict__ si_ws,
    const float* __restrict__ sj_ws, float* __restrict__ out)
{
    __shared__ float sj_l[NN];                        // 2 KB
    __shared__ __align__(16) float alpha_t[NN][TI];   // 16 KB, [j][r]
    __shared__ __align__(16) float part[4][TI][D];    // 16 KB
    __shared__ float redm[TI][4];
    __shared__ float reds[TI][4];

    const int t = threadIdx.x;
    const int w = t >> 6;
    const int lane = t & 63;
    const int bid = blockIdx.x;
    const int b = bid >> 6;
    const int i0 = (bid & 63) << 3;

    sj_l[t] = sj_ws[b * NN + t];
    sj_l[t + 256] = sj_ws[b * NN + t + 256];
    __syncthreads();

    // Phase A: scores from precomputed s_e; thread owns j = t and j = t+256
    float e0[TI], e1[TI];
#pragma unroll
    for (int r = 0; r < TI; ++r) {
        const int i = i0 + r;
        const float siv = si_ws[b * NN + i];
        const float* ser = se_ws + ((size_t)b * NN + i) * NN;
        const float s0 = ser[t];
        const float s1 = ser[t + 256];
        e0[r] = (siv + sj_l[t] + s0) * SCALE;
        e1[r] = (siv + sj_l[t + 256] + s1) * SCALE;
        float m = fmaxf(e0[r], e1[r]);
#pragma unroll
        for (int mm = 32; mm >= 1; mm >>= 1) m = fmaxf(m, __shfl_xor(m, mm));
        if (lane == 0) redm[r][w] = m;
    }
    __syncthreads();

    // Phase B: exp + row sums; unnormalized alpha stored transposed
#pragma unroll
    for (int r = 0; r < TI; ++r) {
        const float mx = fmaxf(fmaxf(redm[r][0], redm[r][1]),
                               fmaxf(redm[r][2], redm[r][3]));
        const float a0 = __expf(e0[r] - mx);
        const float a1 = __expf(e1[r] - mx);
        alpha_t[t][r] = a0;
        alpha_t[t + 256][r] = a1;
        float s = a0 + a1;
#pragma unroll
        for (int mm = 32; mm >= 1; mm >>= 1) s += __shfl_xor(s, mm);
        if (lane == 0) reds[r][w] = s;
    }
    __syncthreads();

    // Phase C: h' = alpha @ h. thread -> 4 consecutive d, 1 of 8 j-groups
    const int dl = (t & 31) << 2;
    const int g = t >> 5;
    float acc[TI][4];
#pragma unroll
    for (int r = 0; r < TI; ++r)
#pragma unroll
        for (int c = 0; c < 4; ++c) acc[r][c] = 0.f;

    const float* hb = h_ws + (size_t)b * NN * D;
    for (int jj = 0; jj < 64; ++jj) {
        const int j = (g << 6) + jj;
        const float4 hv = *(const float4*)(hb + j * D + dl);
        const float4 al0 = *(const float4*)(&alpha_t[j][0]);
        const float4 al1 = *(const float4*)(&alpha_t[j][4]);
        const float ar[TI] = {al0.x, al0.y, al0.z, al0.w, al1.x, al1.y, al1.z, al1.w};
        const float hc[4] = {hv.x, hv.y, hv.z, hv.w};
#pragma unroll
        for (int r = 0; r < TI; ++r)
#pragma unroll
            for (int c = 0; c < 4; ++c) acc[r][c] += ar[r] * hc[c];
    }
#pragma unroll
    for (int r = 0; r < TI; ++r)
#pragma unroll
        for (int c = 0; c < 4; ++c) acc[r][c] += __shfl_xor(acc[r][c], 32);
    if ((t & 63) < 32) {
#pragma unroll
        for (int r = 0; r < TI; ++r)
            *(float4*)&part[w][r][dl] = make_float4(acc[r][0], acc[r][1], acc[r][2], acc[r][3]);
    }
    __syncthreads();

    // Phase D: LayerNorm. wave w handles rows 2w, 2w+1; lane -> d, d+64
#pragma unroll
    for (int rr = 0; rr < 2; ++rr) {
        const int r = w * 2 + rr;
        const float inv = 1.0f / (reds[r][0] + reds[r][1] + reds[r][2] + reds[r][3]);
        const int d0 = lane, d1 = lane + 64;
        const float v0 = (part[0][r][d0] + part[1][r][d0] + part[2][r][d0] + part[3][r][d0]) * inv;
        const float v1 = (part[0][r][d1] + part[1][r][d1] + part[2][r][d1] + part[3][r][d1]) * inv;
        float s = v0 + v1, q = v0 * v0 + v1 * v1;
#pragma unroll
        for (int mm = 32; mm >= 1; mm >>= 1) {
            s += __shfl_xor(s, mm);
            q += __shfl_xor(q, mm);
        }
        const float mu = s * (1.f / 128.f);
        const float var = q * (1.f / 128.f) - mu * mu;
        const float rs = rsqrtf(var + LN_EPS);
        const size_t ob = ((size_t)(b * NN + i0 + r)) * D;
        out[ob + d0] = (v0 - mu) * rs * gamma[d0] + beta[d0];
        out[ob + d1] = (v1 - mu) * rs * gamma[d1] + beta[d1];
    }
}

extern "C" void kernel_launch(void* const* d_in, const int* in_sizes, int n_in,
                              void* d_out, int out_size, void* d_ws, size_t ws_size,
                              hipStream_t stream) {
    const float* x     = (const float*)d_in[0];
    const float* ef    = (const float*)d_in[1];
    const float* W     = (const float*)d_in[2];
    const float* a_src = (const float*)d_in[3];
    const float* a_dst = (const float*)d_in[4];
    const float* a_e   = (const float*)d_in[5];
    const float* gamma = (const float*)d_in[6];
    const float* beta  = (const float*)d_in[7];
    float* out = (float*)d_out;

    float* h_ws  = (float*)d_ws;                       // 2 MiB
    float* si_ws = h_ws + (size_t)NB * NN * D;         // 16 KiB
    float* sj_ws = si_ws + NB * NN;                    // 16 KiB
    float* se_ws = (float*)((char*)d_ws + (4u << 20)); // 8 MiB @ +4 MiB

    // MEASUREMENT ROUND: ke launched 3x (idempotent). dur5 - dur3 = 2*ke.
    ke_scores<<<KE_BLOCKS, 256, 0, stream>>>(ef, a_e, se_ws);
    ke_scores<<<KE_BLOCKS, 256, 0, stream>>>(ef, a_e, se_ws);
    ke_scores<<<KE_BLOCKS, 256, 0, stream>>>(ef, a_e, se_ws);
    k1_proj<<<NB * NN / K1R, 256, 0, stream>>>(x, W, a_src, a_dst, h_ws, si_ws, sj_ws);
    k2_attn<<<NB * (NN / TI), 256, 0, stream>>>(se_ws, gamma, beta,
                                                h_ws, si_ws, sj_ws, out);
}

// Round 6
// 102.198 us; speedup vs baseline: 1.0193x; 1.0193x over previous
//
#include <hip/hip_runtime.h>
#include <math.h>

#define NB 8
#define NN 512
#define D 128
#define TI 8          // query rows per k2 block
#define K1R 8         // rows per k1 block
#define LN_EPS 1e-5f
#define SCALE 0.08838834764831845f  // 1/sqrt(128)

#define KE_BLOCKS 2048
#define KE_NTH (KE_BLOCKS * 256)          // 524288 threads
#define TOT_F4 (NB * NN * NN * 4)         // 8388608 float4 in edge_feats

typedef float f32x4 __attribute__((ext_vector_type(4)));

__device__ __forceinline__ float dotv(f32x4 a, f32x4 b) {
    f32x4 m = a * b;
    return m.x + m.y + m.z + m.w;
}
__device__ __forceinline__ float dot4(float4 a, float4 b) {
    return a.x * b.x + a.y * b.y + a.z * b.z + a.w * b.w;
}

// ---------------- Kernel E: s_e[b,i,j] = edge_feats[b,i,j,:] . a_e ----------
__global__ __launch_bounds__(256) void ke_scores(
    const float* __restrict__ ef, const float* __restrict__ a_e,
    float* __restrict__ se_ws)
{
    const int g = blockIdx.x * 256 + threadIdx.x;
    const int c = g & 3;
    const f32x4 A = ((const f32x4*)a_e)[c];
    const f32x4* ef4 = (const f32x4*)ef;
#pragma unroll 4
    for (int k = 0; k < TOT_F4 / KE_NTH; ++k) {
        const size_t f = (size_t)k * KE_NTH + g;
        const f32x4 v = ef4[f];
        float p = dotv(v, A);
        p += __shfl_xor(p, 1);
        p += __shfl_xor(p, 2);
        if (c == 0) se_ws[f >> 2] = p;
    }
}

// ---------------- Kernel 1: h = x @ W^T, s_i, s_j ---------------------------
__global__ __launch_bounds__(256) void k1_proj(
    const float* __restrict__ x, const float* __restrict__ W,
    const float* __restrict__ a_src, const float* __restrict__ a_dst,
    float* __restrict__ h_ws, float* __restrict__ si_ws, float* __restrict__ sj_ws)
{
    __shared__ __align__(16) float4 Wl[128][32];   // [o][q ^ (o&7)] swizzle
    __shared__ __align__(16) float4 xl[K1R][32];
    __shared__ float redk[K1R][2][2];

    const int t = threadIdx.x;
    const int row0 = blockIdx.x * K1R;

    const float4* Wg = (const float4*)W;
#pragma unroll
    for (int k = 0; k < 16; ++k) {
        const int f = t + 256 * k;
        const int o = f >> 5, q = f & 31;
        Wl[o][q ^ (o & 7)] = Wg[f];
    }
    xl[t >> 5][t & 31] = ((const float4*)(x + (size_t)row0 * D))[t];
    __syncthreads();

    const int o = t & 127;
    const int rb = (t >> 7) * (K1R / 2);
    float acc[K1R / 2] = {0.f, 0.f, 0.f, 0.f};
#pragma unroll
    for (int q = 0; q < 32; ++q) {
        const float4 wv = Wl[o][q ^ (o & 7)];
#pragma unroll
        for (int r = 0; r < K1R / 2; ++r) acc[r] += dot4(wv, xl[rb + r][q]);
    }
    const float as = a_src[o], ad = a_dst[o];
#pragma unroll
    for (int r = 0; r < K1R / 2; ++r) {
        h_ws[(size_t)(row0 + rb + r) * D + o] = acc[r];
        float vs = acc[r] * as, vd = acc[r] * ad;
#pragma unroll
        for (int m = 32; m >= 1; m >>= 1) {
            vs += __shfl_xor(vs, m);
            vd += __shfl_xor(vd, m);
        }
        if ((t & 63) == 0) {
            redk[rb + r][0][(t >> 6) & 1] = vs;
            redk[rb + r][1][(t >> 6) & 1] = vd;
        }
    }
    __syncthreads();
    if (t < K1R) si_ws[row0 + t] = redk[t][0][0] + redk[t][0][1];
    else if (t < 2 * K1R) {
        const int r = t - K1R;
        sj_ws[row0 + r] = redk[r][1][0] + redk[r][1][1];
    }
}

// ---------------- Kernel 2: softmax + PV + LayerNorm ------------------------
// alpha now [TI][NN] (conflict-free stores, broadcast b128 reads).
// Phase C: 16 iters x {4 hv loads batched + 8 broadcast alpha b128 + 128 FMA}.
__global__ __launch_bounds__(256) void k2_attn(
    const float* __restrict__ se_ws,
    const float* __restrict__ gamma, const float* __restrict__ beta,
    const float* __restrict__ h_ws, const float* __restrict__ si_ws,
    const float* __restrict__ sj_ws, float* __restrict__ out)
{
    __shared__ float sj_l[NN];                        // 2 KB
    __shared__ __align__(16) float alpha_t[TI][NN];   // 16 KB, [r][j]
    __shared__ __align__(16) float part[4][TI][D];    // 16 KB
    __shared__ float redm[TI][4];
    __shared__ float reds[TI][4];

    const int t = threadIdx.x;
    const int w = t >> 6;
    const int lane = t & 63;
    const int bid = blockIdx.x;
    const int b = bid >> 6;
    const int i0 = (bid & 63) << 3;

    sj_l[t] = sj_ws[b * NN + t];
    sj_l[t + 256] = sj_ws[b * NN + t + 256];
    __syncthreads();

    // Phase A: scores from precomputed s_e; thread owns j = t and j = t+256
    float e0[TI], e1[TI];
#pragma unroll
    for (int r = 0; r < TI; ++r) {
        const int i = i0 + r;
        const float siv = si_ws[b * NN + i];
        const float* ser = se_ws + ((size_t)b * NN + i) * NN;
        const float s0 = ser[t];
        const float s1 = ser[t + 256];
        e0[r] = (siv + sj_l[t] + s0) * SCALE;
        e1[r] = (siv + sj_l[t + 256] + s1) * SCALE;
        float m = fmaxf(e0[r], e1[r]);
#pragma unroll
        for (int mm = 32; mm >= 1; mm >>= 1) m = fmaxf(m, __shfl_xor(m, mm));
        if (lane == 0) redm[r][w] = m;
    }
    __syncthreads();

    // Phase B: exp + row sums; alpha stored [r][j] (lane-consecutive words)
#pragma unroll
    for (int r = 0; r < TI; ++r) {
        const float mx = fmaxf(fmaxf(redm[r][0], redm[r][1]),
                               fmaxf(redm[r][2], redm[r][3]));
        const float a0 = __expf(e0[r] - mx);
        const float a1 = __expf(e1[r] - mx);
        alpha_t[r][t] = a0;
        alpha_t[r][t + 256] = a1;
        float s = a0 + a1;
#pragma unroll
        for (int mm = 32; mm >= 1; mm >>= 1) s += __shfl_xor(s, mm);
        if (lane == 0) reds[r][w] = s;
    }
    __syncthreads();

    // Phase C: h' = alpha @ h. thread -> 4 consecutive d, 1 of 8 j-groups,
    // 4 j per iteration (batched loads for ILP).
    const int dl = (t & 31) << 2;
    const int g = t >> 5;
    float acc[TI][4];
#pragma unroll
    for (int r = 0; r < TI; ++r)
#pragma unroll
        for (int c = 0; c < 4; ++c) acc[r][c] = 0.f;

    const float* hb = h_ws + (size_t)b * NN * D;
#pragma unroll 4
    for (int jt = 0; jt < 16; ++jt) {
        const int j0 = (g << 6) + (jt << 2);
        float4 hv0 = *(const float4*)(hb + (size_t)(j0 + 0) * D + dl);
        float4 hv1 = *(const float4*)(hb + (size_t)(j0 + 1) * D + dl);
        float4 hv2 = *(const float4*)(hb + (size_t)(j0 + 2) * D + dl);
        float4 hv3 = *(const float4*)(hb + (size_t)(j0 + 3) * D + dl);
#pragma unroll
        for (int r = 0; r < TI; ++r) {
            const float4 av = *(const float4*)&alpha_t[r][j0];
            acc[r][0] += av.x * hv0.x + av.y * hv1.x + av.z * hv2.x + av.w * hv3.x;
            acc[r][1] += av.x * hv0.y + av.y * hv1.y + av.z * hv2.y + av.w * hv3.y;
            acc[r][2] += av.x * hv0.z + av.y * hv1.z + av.z * hv2.z + av.w * hv3.z;
            acc[r][3] += av.x * hv0.w + av.y * hv1.w + av.z * hv2.w + av.w * hv3.w;
        }
    }
#pragma unroll
    for (int r = 0; r < TI; ++r)
#pragma unroll
        for (int c = 0; c < 4; ++c) acc[r][c] += __shfl_xor(acc[r][c], 32);
    if ((t & 63) < 32) {
#pragma unroll
        for (int r = 0; r < TI; ++r)
            *(float4*)&part[w][r][dl] = make_float4(acc[r][0], acc[r][1], acc[r][2], acc[r][3]);
    }
    __syncthreads();

    // Phase D: LayerNorm. wave w handles rows 2w, 2w+1; lane -> d, d+64
#pragma unroll
    for (int rr = 0; rr < 2; ++rr) {
        const int r = w * 2 + rr;
        const float inv = 1.0f / (reds[r][0] + reds[r][1] + reds[r][2] + reds[r][3]);
        const int d0 = lane, d1 = lane + 64;
        const float v0 = (part[0][r][d0] + part[1][r][d0] + part[2][r][d0] + part[3][r][d0]) * inv;
        const float v1 = (part[0][r][d1] + part[1][r][d1] + part[2][r][d1] + part[3][r][d1]) * inv;
        float s = v0 + v1, q = v0 * v0 + v1 * v1;
#pragma unroll
        for (int mm = 32; mm >= 1; mm >>= 1) {
            s += __shfl_xor(s, mm);
            q += __shfl_xor(q, mm);
        }
        const float mu = s * (1.f / 128.f);
        const float var = q * (1.f / 128.f) - mu * mu;
        const float rs = rsqrtf(var + LN_EPS);
        const size_t ob = ((size_t)(b * NN + i0 + r)) * D;
        out[ob + d0] = (v0 - mu) * rs * gamma[d0] + beta[d0];
        out[ob + d1] = (v1 - mu) * rs * gamma[d1] + beta[d1];
    }
}

extern "C" void kernel_launch(void* const* d_in, const int* in_sizes, int n_in,
                              void* d_out, int out_size, void* d_ws, size_t ws_size,
                              hipStream_t stream) {
    const float* x     = (const float*)d_in[0];
    const float* ef    = (const float*)d_in[1];
    const float* W     = (const float*)d_in[2];
    const float* a_src = (const float*)d_in[3];
    const float* a_dst = (const float*)d_in[4];
    const float* a_e   = (const float*)d_in[5];
    const float* gamma = (const float*)d_in[6];
    const float* beta  = (const float*)d_in[7];
    float* out = (float*)d_out;

    float* h_ws  = (float*)d_ws;                       // 2 MiB
    float* si_ws = h_ws + (size_t)NB * NN * D;
    float* sj_ws = si_ws + NB * NN;
    float* se_ws = (float*)((char*)d_ws + (4u << 20)); // 8 MiB @ +4 MiB

    ke_scores<<<KE_BLOCKS, 256, 0, stream>>>(ef, a_e, se_ws);
    k1_proj<<<NB * NN / K1R, 256, 0, stream>>>(x, W, a_src, a_dst, h_ws, si_ws, sj_ws);
    // MEASUREMENT: k2 launched 3x (idempotent). dur6 - (O + ke + k1) = 3*k2_new.
    k2_attn<<<NB * (NN / TI), 256, 0, stream>>>(se_ws, gamma, beta,
                                                h_ws, si_ws, sj_ws, out);
    k2_attn<<<NB * (NN / TI), 256, 0, stream>>>(se_ws, gamma, beta,
                                                h_ws, si_ws, sj_ws, out);
    k2_attn<<<NB * (NN / TI), 256, 0, stream>>>(se_ws, gamma, beta,
                                                h_ws, si_ws, sj_ws, out);
}

// Round 7
// 59.127 us; speedup vs baseline: 1.7617x; 1.7284x over previous
//
#include <hip/hip_runtime.h>
#include <math.h>

#define NB 8
#define NN 512
#define D 128
#define TI 8          // query rows per k2 block
#define K1R 8         // rows per k1 block
#define LN_EPS 1e-5f
#define SCALE 0.08838834764831845f  // 1/sqrt(128)

#define KE_BLOCKS 2048
#define KE_NTH (KE_BLOCKS * 256)          // 524288 threads
#define TOT_F4 (NB * NN * NN * 4)         // 8388608 float4 in edge_feats

typedef float f32x4 __attribute__((ext_vector_type(4)));

__device__ __forceinline__ float dotv(f32x4 a, f32x4 b) {
    f32x4 m = a * b;
    return m.x + m.y + m.z + m.w;
}
__device__ __forceinline__ float dot4(float4 a, float4 b) {
    return a.x * b.x + a.y * b.y + a.z * b.z + a.w * b.w;
}

// ---------------- Kernel E: s_e[b,i,j] = edge_feats[b,i,j,:] . a_e ----------
// (byte-identical to round 6; in-situ cost pinned at ~21.5 us = HBM roofline)
__global__ __launch_bounds__(256) void ke_scores(
    const float* __restrict__ ef, const float* __restrict__ a_e,
    float* __restrict__ se_ws)
{
    const int g = blockIdx.x * 256 + threadIdx.x;
    const int c = g & 3;
    const f32x4 A = ((const f32x4*)a_e)[c];
    const f32x4* ef4 = (const f32x4*)ef;
#pragma unroll 4
    for (int k = 0; k < TOT_F4 / KE_NTH; ++k) {
        const size_t f = (size_t)k * KE_NTH + g;
        const f32x4 v = ef4[f];
        float p = dotv(v, A);
        p += __shfl_xor(p, 1);
        p += __shfl_xor(p, 2);
        if (c == 0) se_ws[f >> 2] = p;
    }
}

// ---------------- Kernel 1: h = x @ W^T, s_i, s_j (unchanged) ---------------
__global__ __launch_bounds__(256) void k1_proj(
    const float* __restrict__ x, const float* __restrict__ W,
    const float* __restrict__ a_src, const float* __restrict__ a_dst,
    float* __restrict__ h_ws, float* __restrict__ si_ws, float* __restrict__ sj_ws)
{
    __shared__ __align__(16) float4 Wl[128][32];   // [o][q ^ (o&7)] swizzle
    __shared__ __align__(16) float4 xl[K1R][32];
    __shared__ float redk[K1R][2][2];

    const int t = threadIdx.x;
    const int row0 = blockIdx.x * K1R;

    const float4* Wg = (const float4*)W;
#pragma unroll
    for (int k = 0; k < 16; ++k) {
        const int f = t + 256 * k;
        const int o = f >> 5, q = f & 31;
        Wl[o][q ^ (o & 7)] = Wg[f];
    }
    xl[t >> 5][t & 31] = ((const float4*)(x + (size_t)row0 * D))[t];
    __syncthreads();

    const int o = t & 127;
    const int rb = (t >> 7) * (K1R / 2);
    float acc[K1R / 2] = {0.f, 0.f, 0.f, 0.f};
#pragma unroll
    for (int q = 0; q < 32; ++q) {
        const float4 wv = Wl[o][q ^ (o & 7)];
#pragma unroll
        for (int r = 0; r < K1R / 2; ++r) acc[r] += dot4(wv, xl[rb + r][q]);
    }
    const float as = a_src[o], ad = a_dst[o];
#pragma unroll
    for (int r = 0; r < K1R / 2; ++r) {
        h_ws[(size_t)(row0 + rb + r) * D + o] = acc[r];
        float vs = acc[r] * as, vd = acc[r] * ad;
#pragma unroll
        for (int m = 32; m >= 1; m >>= 1) {
            vs += __shfl_xor(vs, m);
            vd += __shfl_xor(vd, m);
        }
        if ((t & 63) == 0) {
            redk[rb + r][0][(t >> 6) & 1] = vs;
            redk[rb + r][1][(t >> 6) & 1] = vd;
        }
    }
    __syncthreads();
    if (t < K1R) si_ws[row0 + t] = redk[t][0][0] + redk[t][0][1];
    else if (t < 2 * K1R) {
        const int r = t - K1R;
        sj_ws[row0 + r] = redk[r][1][0] + redk[r][1][1];
    }
}

// ---------------- Kernel 2 v7: 512 threads, vectorized scores ---------------
// grid: 512 blocks (TI=8 rows each), block: 512 (8 waves -> 4 waves/SIMD)
__global__ __launch_bounds__(512) void k2_attn(
    const float* __restrict__ se_ws,
    const float* __restrict__ gamma, const float* __restrict__ beta,
    const float* __restrict__ h_ws, const float* __restrict__ si_ws,
    const float* __restrict__ sj_ws, float* __restrict__ out)
{
    __shared__ float sj_l[NN];                        // 2 KB
    __shared__ __align__(16) float alpha[TI][NN];     // 16 KB, [r][j]
    __shared__ __align__(16) float part[8][TI][D];    // 32 KB (per-wave PV)
    __shared__ float redm[TI][2];
    __shared__ float reds[TI][2];

    const int t = threadIdx.x;
    const int w = t >> 6;             // wave 0..7
    const int lane = t & 63;
    const int bid = blockIdx.x;
    const int b = bid >> 6;
    const int i0 = (bid & 63) << 3;

    sj_l[t] = sj_ws[b * NN + t];
    __syncthreads();

    // ---- Phase A: scores, vectorized. thread -> j-quad q for row pair rg.
    const int q = t & 127;            // j0 = 4q
    const int rg = t >> 7;            // row pair 0..3
    const int r0 = rg * 2, r1 = rg * 2 + 1;
    const int wh = (t >> 6) & 1;      // which wave of the pair
    const float si0 = si_ws[b * NN + i0 + r0];
    const float si1 = si_ws[b * NN + i0 + r1];
    const f32x4 se0 = *(const f32x4*)(se_ws + ((size_t)b * NN + i0 + r0) * NN + 4 * q);
    const f32x4 se1 = *(const f32x4*)(se_ws + ((size_t)b * NN + i0 + r1) * NN + 4 * q);
    const f32x4 sjv = *(const f32x4*)&sj_l[4 * q];
    const f32x4 e0 = (si0 + sjv + se0) * SCALE;
    const f32x4 e1 = (si1 + sjv + se1) * SCALE;
    float m0 = fmaxf(fmaxf(e0.x, e0.y), fmaxf(e0.z, e0.w));
    float m1 = fmaxf(fmaxf(e1.x, e1.y), fmaxf(e1.z, e1.w));
#pragma unroll
    for (int mm = 32; mm >= 1; mm >>= 1) {
        m0 = fmaxf(m0, __shfl_xor(m0, mm));
        m1 = fmaxf(m1, __shfl_xor(m1, mm));
    }
    if (lane == 0) { redm[r0][wh] = m0; redm[r1][wh] = m1; }
    __syncthreads();

    // ---- Phase B: exp + row sums; alpha [r][j] float4 stores
    {
        const float mx0 = fmaxf(redm[r0][0], redm[r0][1]);
        const float mx1 = fmaxf(redm[r1][0], redm[r1][1]);
        f32x4 a0, a1;
        a0.x = __expf(e0.x - mx0); a0.y = __expf(e0.y - mx0);
        a0.z = __expf(e0.z - mx0); a0.w = __expf(e0.w - mx0);
        a1.x = __expf(e1.x - mx1); a1.y = __expf(e1.y - mx1);
        a1.z = __expf(e1.z - mx1); a1.w = __expf(e1.w - mx1);
        *(f32x4*)&alpha[r0][4 * q] = a0;
        *(f32x4*)&alpha[r1][4 * q] = a1;
        float s0 = a0.x + a0.y + a0.z + a0.w;
        float s1 = a1.x + a1.y + a1.z + a1.w;
#pragma unroll
        for (int mm = 32; mm >= 1; mm >>= 1) {
            s0 += __shfl_xor(s0, mm);
            s1 += __shfl_xor(s1, mm);
        }
        if (lane == 0) { reds[r0][wh] = s0; reds[r1][wh] = s1; }
    }
    __syncthreads();

    // ---- Phase C: h' = alpha @ h. 16 j-groups of 32; thread -> 4 d-cols.
    const int dl = (t & 31) << 2;
    const int g = t >> 5;             // 0..15
    float acc[TI][4];
#pragma unroll
    for (int r = 0; r < TI; ++r)
#pragma unroll
        for (int c = 0; c < 4; ++c) acc[r][c] = 0.f;

    const float* hb = h_ws + (size_t)b * NN * D;
#pragma unroll 2
    for (int jt = 0; jt < 8; ++jt) {
        const int j0 = (g << 5) + (jt << 2);
        float4 hv0 = *(const float4*)(hb + (size_t)(j0 + 0) * D + dl);
        float4 hv1 = *(const float4*)(hb + (size_t)(j0 + 1) * D + dl);
        float4 hv2 = *(const float4*)(hb + (size_t)(j0 + 2) * D + dl);
        float4 hv3 = *(const float4*)(hb + (size_t)(j0 + 3) * D + dl);
#pragma unroll
        for (int r = 0; r < TI; ++r) {
            const f32x4 av = *(const f32x4*)&alpha[r][j0];
            acc[r][0] += av.x * hv0.x + av.y * hv1.x + av.z * hv2.x + av.w * hv3.x;
            acc[r][1] += av.x * hv0.y + av.y * hv1.y + av.z * hv2.y + av.w * hv3.y;
            acc[r][2] += av.x * hv0.z + av.y * hv1.z + av.z * hv2.z + av.w * hv3.z;
            acc[r][3] += av.x * hv0.w + av.y * hv1.w + av.z * hv2.w + av.w * hv3.w;
        }
    }
#pragma unroll
    for (int r = 0; r < TI; ++r)
#pragma unroll
        for (int c = 0; c < 4; ++c) acc[r][c] += __shfl_xor(acc[r][c], 32);
    if (lane < 32) {
#pragma unroll
        for (int r = 0; r < TI; ++r)
            *(float4*)&part[w][r][dl] = make_float4(acc[r][0], acc[r][1], acc[r][2], acc[r][3]);
    }
    __syncthreads();

    // ---- Phase D: LayerNorm. wave w -> row w; lane -> d, d+64
    {
        const int r = w;
        const float inv = 1.0f / (reds[r][0] + reds[r][1]);
        const int d0 = lane, d1 = lane + 64;
        float v0 = 0.f, v1 = 0.f;
#pragma unroll
        for (int pw = 0; pw < 8; ++pw) {
            v0 += part[pw][r][d0];
            v1 += part[pw][r][d1];
        }
        v0 *= inv; v1 *= inv;
        float s = v0 + v1, qq = v0 * v0 + v1 * v1;
#pragma unroll
        for (int mm = 32; mm >= 1; mm >>= 1) {
            s += __shfl_xor(s, mm);
            qq += __shfl_xor(qq, mm);
        }
        const float mu = s * (1.f / 128.f);
        const float var = qq * (1.f / 128.f) - mu * mu;
        const float rs = rsqrtf(var + LN_EPS);
        const size_t ob = ((size_t)(b * NN + i0 + r)) * D;
        out[ob + d0] = (v0 - mu) * rs * gamma[d0] + beta[d0];
        out[ob + d1] = (v1 - mu) * rs * gamma[d1] + beta[d1];
    }
}

extern "C" void kernel_launch(void* const* d_in, const int* in_sizes, int n_in,
                              void* d_out, int out_size, void* d_ws, size_t ws_size,
                              hipStream_t stream) {
    const float* x     = (const float*)d_in[0];
    const float* ef    = (const float*)d_in[1];
    const float* W     = (const float*)d_in[2];
    const float* a_src = (const float*)d_in[3];
    const float* a_dst = (const float*)d_in[4];
    const float* a_e   = (const float*)d_in[5];
    const float* gamma = (const float*)d_in[6];
    const float* beta  = (const float*)d_in[7];
    float* out = (float*)d_out;

    float* h_ws  = (float*)d_ws;                       // 2 MiB
    float* si_ws = h_ws + (size_t)NB * NN * D;
    float* sj_ws = si_ws + NB * NN;
    float* se_ws = (float*)((char*)d_ws + (4u << 20)); // 8 MiB @ +4 MiB

    ke_scores<<<KE_BLOCKS, 256, 0, stream>>>(ef, a_e, se_ws);
    k1_proj<<<NB * NN / K1R, 256, 0, stream>>>(x, W, a_src, a_dst, h_ws, si_ws, sj_ws);
    k2_attn<<<NB * (NN / TI), 512, 0, stream>>>(se_ws, gamma, beta,
                                                h_ws, si_ws, sj_ws, out);
}

// Round 9
// 55.435 us; speedup vs baseline: 1.8791x; 1.0666x over previous
//
#include <hip/hip_runtime.h>
#include <math.h>

#define NB 8
#define NN 512
#define D 128
#define TIF 4         // query rows per fused block
#define K1R 8         // rows per k1 block
#define LN_EPS 1e-5f
#define SCALE 0.08838834764831845f  // 1/sqrt(128)

typedef float f32x4 __attribute__((ext_vector_type(4)));

__device__ __forceinline__ float dotv(f32x4 a, f32x4 b) {
    f32x4 m = a * b;
    return m.x + m.y + m.z + m.w;
}
__device__ __forceinline__ float dot4(float4 a, float4 b) {
    return a.x * b.x + a.y * b.y + a.z * b.z + a.w * b.w;
}

// ---------------- Kernel 1: h = x @ W^T, s_i, s_j (unchanged) ---------------
__global__ __launch_bounds__(256) void k1_proj(
    const float* __restrict__ x, const float* __restrict__ W,
    const float* __restrict__ a_src, const float* __restrict__ a_dst,
    float* __restrict__ h_ws, float* __restrict__ si_ws, float* __restrict__ sj_ws)
{
    __shared__ __align__(16) float4 Wl[128][32];   // [o][q ^ (o&7)] swizzle
    __shared__ __align__(16) float4 xl[K1R][32];
    __shared__ float redk[K1R][2][2];

    const int t = threadIdx.x;
    const int row0 = blockIdx.x * K1R;

    const float4* Wg = (const float4*)W;
#pragma unroll
    for (int k = 0; k < 16; ++k) {
        const int f = t + 256 * k;
        const int o = f >> 5, q = f & 31;
        Wl[o][q ^ (o & 7)] = Wg[f];
    }
    xl[t >> 5][t & 31] = ((const float4*)(x + (size_t)row0 * D))[t];
    __syncthreads();

    const int o = t & 127;
    const int rb = (t >> 7) * (K1R / 2);
    float acc[K1R / 2] = {0.f, 0.f, 0.f, 0.f};
#pragma unroll
    for (int q = 0; q < 32; ++q) {
        const float4 wv = Wl[o][q ^ (o & 7)];
#pragma unroll
        for (int r = 0; r < K1R / 2; ++r) acc[r] += dot4(wv, xl[rb + r][q]);
    }
    const float as = a_src[o], ad = a_dst[o];
#pragma unroll
    for (int r = 0; r < K1R / 2; ++r) {
        h_ws[(size_t)(row0 + rb + r) * D + o] = acc[r];
        float vs = acc[r] * as, vd = acc[r] * ad;
#pragma unroll
        for (int m = 32; m >= 1; m >>= 1) {
            vs += __shfl_xor(vs, m);
            vd += __shfl_xor(vd, m);
        }
        if ((t & 63) == 0) {
            redk[rb + r][0][(t >> 6) & 1] = vs;
            redk[rb + r][1][(t >> 6) & 1] = vd;
        }
    }
    __syncthreads();
    if (t < K1R) si_ws[row0 + t] = redk[t][0][0] + redk[t][0][1];
    else if (t < 2 * K1R) {
        const int r = t - K1R;
        sj_ws[row0 + r] = redk[r][1][0] + redk[r][1][1];
    }
}

// ---------------- Fused kernel: stream ef slice -> scores -> softmax -> PV -> LN
// grid: NB * NN / TIF = 1024 blocks, block: 256 (4 waves)
// BUGFIX vs round 8: part is [4] waves (256 threads), Phase D sums 4 partials.
__global__ __launch_bounds__(256, 4) void kfused(
    const float* __restrict__ ef, const float* __restrict__ a_e,
    const float* __restrict__ gamma, const float* __restrict__ beta,
    const float* __restrict__ h_ws, const float* __restrict__ si_ws,
    const float* __restrict__ sj_ws, float* __restrict__ out)
{
    __shared__ float sj_l[NN];                         // 2 KB
    __shared__ __align__(16) float sa[TIF][NN];        // 8 KB: se -> alpha in place
    __shared__ __align__(16) float part[4][TIF][D];    // 8 KB per-wave PV partials
    __shared__ float redm[TIF][2];
    __shared__ float reds[TIF][2];

    const int t = threadIdx.x;
    const int w = t >> 6;
    const int lane = t & 63;
    const int bid = blockIdx.x;
    const int b = bid >> 7;              // 128 blocks per batch
    const int i0 = (bid & 127) * TIF;

    sj_l[t] = sj_ws[b * NN + t];
    sj_l[t + 256] = sj_ws[b * NN + t + 256];

    // ---- Stage 1: stream own ef slice, reduce to edge scores in LDS.
    const int c = t & 3;
    const f32x4 A = ((const f32x4*)a_e)[c];
    const f32x4* ef4 = (const f32x4*)ef + ((size_t)b * NN + i0) * NN * 4;
    float* saf = &sa[0][0];
#pragma unroll 8
    for (int k = 0; k < 32; ++k) {
        const int f = 256 * k + t;
        const f32x4 v = ef4[f];
        float p = dotv(v, A);
        p += __shfl_xor(p, 1);
        p += __shfl_xor(p, 2);
        if (c == 0) saf[f >> 2] = p;     // sa[i_off][j]
    }
    __syncthreads();

    // ---- Phase A: e = (si + sj + se) * scale; row max.
    const int q = t & 127;
    const int rp = t >> 7;
    const int r0 = 2 * rp, r1 = 2 * rp + 1;
    const int wh = (t >> 6) & 1;
    const float si0 = si_ws[b * NN + i0 + r0];
    const float si1 = si_ws[b * NN + i0 + r1];
    const f32x4 sjv = *(const f32x4*)&sj_l[4 * q];
    const f32x4 e0 = (si0 + sjv + *(const f32x4*)&sa[r0][4 * q]) * SCALE;
    const f32x4 e1 = (si1 + sjv + *(const f32x4*)&sa[r1][4 * q]) * SCALE;
    float m0 = fmaxf(fmaxf(e0.x, e0.y), fmaxf(e0.z, e0.w));
    float m1 = fmaxf(fmaxf(e1.x, e1.y), fmaxf(e1.z, e1.w));
#pragma unroll
    for (int mm = 32; mm >= 1; mm >>= 1) {
        m0 = fmaxf(m0, __shfl_xor(m0, mm));
        m1 = fmaxf(m1, __shfl_xor(m1, mm));
    }
    if (lane == 0) { redm[r0][wh] = m0; redm[r1][wh] = m1; }
    __syncthreads();

    // ---- Phase B: exp + row sums; alpha overwrites sa in place.
    {
        const float mx0 = fmaxf(redm[r0][0], redm[r0][1]);
        const float mx1 = fmaxf(redm[r1][0], redm[r1][1]);
        f32x4 a0, a1;
        a0.x = __expf(e0.x - mx0); a0.y = __expf(e0.y - mx0);
        a0.z = __expf(e0.z - mx0); a0.w = __expf(e0.w - mx0);
        a1.x = __expf(e1.x - mx1); a1.y = __expf(e1.y - mx1);
        a1.z = __expf(e1.z - mx1); a1.w = __expf(e1.w - mx1);
        *(f32x4*)&sa[r0][4 * q] = a0;
        *(f32x4*)&sa[r1][4 * q] = a1;
        float s0 = a0.x + a0.y + a0.z + a0.w;
        float s1 = a1.x + a1.y + a1.z + a1.w;
#pragma unroll
        for (int mm = 32; mm >= 1; mm >>= 1) {
            s0 += __shfl_xor(s0, mm);
            s1 += __shfl_xor(s1, mm);
        }
        if (lane == 0) { reds[r0][wh] = s0; reds[r1][wh] = s1; }
    }
    __syncthreads();

    // ---- Phase C: h' = alpha @ h. 8 j-groups of 64; thread -> 4 d-cols.
    const int dl = (t & 31) << 2;
    const int g = t >> 5;               // 0..7
    float acc[TIF][4];
#pragma unroll
    for (int r = 0; r < TIF; ++r)
#pragma unroll
        for (int cc = 0; cc < 4; ++cc) acc[r][cc] = 0.f;

    const float* hb = h_ws + (size_t)b * NN * D;
#pragma unroll 2
    for (int jt = 0; jt < 16; ++jt) {
        const int j0 = (g << 6) + (jt << 2);
        float4 hv0 = *(const float4*)(hb + (size_t)(j0 + 0) * D + dl);
        float4 hv1 = *(const float4*)(hb + (size_t)(j0 + 1) * D + dl);
        float4 hv2 = *(const float4*)(hb + (size_t)(j0 + 2) * D + dl);
        float4 hv3 = *(const float4*)(hb + (size_t)(j0 + 3) * D + dl);
#pragma unroll
        for (int r = 0; r < TIF; ++r) {
            const f32x4 av = *(const f32x4*)&sa[r][j0];
            acc[r][0] += av.x * hv0.x + av.y * hv1.x + av.z * hv2.x + av.w * hv3.x;
            acc[r][1] += av.x * hv0.y + av.y * hv1.y + av.z * hv2.y + av.w * hv3.y;
            acc[r][2] += av.x * hv0.z + av.y * hv1.z + av.z * hv2.z + av.w * hv3.z;
            acc[r][3] += av.x * hv0.w + av.y * hv1.w + av.z * hv2.w + av.w * hv3.w;
        }
    }
#pragma unroll
    for (int r = 0; r < TIF; ++r)
#pragma unroll
        for (int cc = 0; cc < 4; ++cc) acc[r][cc] += __shfl_xor(acc[r][cc], 32);
    if (lane < 32) {
#pragma unroll
        for (int r = 0; r < TIF; ++r)
            *(float4*)&part[w][r][dl] = make_float4(acc[r][0], acc[r][1], acc[r][2], acc[r][3]);
    }
    __syncthreads();

    // ---- Phase D: LayerNorm. waves 0..3 -> rows 0..3; lane -> d, d+64.
    {
        const int r = w;
        const float inv = 1.0f / (reds[r][0] + reds[r][1]);
        const int d0 = lane, d1 = lane + 64;
        float v0 = 0.f, v1 = 0.f;
#pragma unroll
        for (int pw = 0; pw < 4; ++pw) {     // 4 waves only (BUGFIX)
            v0 += part[pw][r][d0];
            v1 += part[pw][r][d1];
        }
        v0 *= inv; v1 *= inv;
        float s = v0 + v1, qq = v0 * v0 + v1 * v1;
#pragma unroll
        for (int mm = 32; mm >= 1; mm >>= 1) {
            s += __shfl_xor(s, mm);
            qq += __shfl_xor(qq, mm);
        }
        const float mu = s * (1.f / 128.f);
        const float var = qq * (1.f / 128.f) - mu * mu;
        const float rs = rsqrtf(var + LN_EPS);
        const size_t ob = ((size_t)(b * NN + i0 + r)) * D;
        out[ob + d0] = (v0 - mu) * rs * gamma[d0] + beta[d0];
        out[ob + d1] = (v1 - mu) * rs * gamma[d1] + beta[d1];
    }
}

extern "C" void kernel_launch(void* const* d_in, const int* in_sizes, int n_in,
                              void* d_out, int out_size, void* d_ws, size_t ws_size,
                              hipStream_t stream) {
    const float* x     = (const float*)d_in[0];
    const float* ef    = (const float*)d_in[1];
    const float* W     = (const float*)d_in[2];
    const float* a_src = (const float*)d_in[3];
    const float* a_dst = (const float*)d_in[4];
    const float* a_e   = (const float*)d_in[5];
    const float* gamma = (const float*)d_in[6];
    const float* beta  = (const float*)d_in[7];
    float* out = (float*)d_out;

    float* h_ws  = (float*)d_ws;                       // 2 MiB
    float* si_ws = h_ws + (size_t)NB * NN * D;
    float* sj_ws = si_ws + NB * NN;

    k1_proj<<<NB * NN / K1R, 256, 0, stream>>>(x, W, a_src, a_dst, h_ws, si_ws, sj_ws);
    kfused<<<NB * NN / TIF, 256, 0, stream>>>(ef, a_e, gamma, beta,
                                              h_ws, si_ws, sj_ws, out);
}